// Round 25
// baseline (65.418 us; speedup 1.0000x reference)
//
#include <hip/hip_runtime.h>
#include <hip/hip_bf16.h>

#define N_NODES 50000
#define N_EDGES 600000
#define DIM 128
#define NBUCK 782         // buckets (dst>>6), 64 nodes each
#define BNODES 64
#define CAPL 40           // LDS slots per node; P(deg>40|Poisson(12)) ~ 1e-10
#define SEGB 16           // per-(block,bucket) cell capacity; lambda ~ 1.97
#define WLDS_STRIDE 136
#define EPB 1536          // edges per gemm block (512 thr x 3); 391*1536 >= 600k
#define GEMM_BLOCKS 391

typedef __attribute__((ext_vector_type(8))) short bf16x8;
typedef __attribute__((ext_vector_type(4))) float floatx4;

// ---------------- prep: Wt[n][k] = bf16(W[k][n]) (verbatim r22/r24) ----------
__global__ __launch_bounds__(256) void k_prep(const float* __restrict__ W,
                                              ushort* __restrict__ Wt) {
    int idx = (blockIdx.x * 256 + threadIdx.x) * 4;
    float4 v = *(const float4*)(W + idx);
    int k = idx >> 7, n = idx & 127;
    Wt[(size_t)(n + 0) * DIM + k] = __bfloat16_as_ushort(__float2bfloat16(v.x));
    Wt[(size_t)(n + 1) * DIM + k] = __bfloat16_as_ushort(__float2bfloat16(v.y));
    Wt[(size_t)(n + 2) * DIM + k] = __bfloat16_as_ushort(__float2bfloat16(v.z));
    Wt[(size_t)(n + 3) * DIM + k] = __bfloat16_as_ushort(__float2bfloat16(v.w));
}

// ---------------- fused MFMA GEMM + phase-A bucketing (64-node buckets) ------
// gemm body verbatim r16/r18/r24 (proven). Scatter: edge -> cell
// seg[b][dst>>6][<=16], positions from LDS counters (no global atomics).
// cntAB layout [bucket][block] so bingather's count read is coalesced.
__global__ __launch_bounds__(512) void k_gemm_fill(
        const float* __restrict__ X,
        const ushort* __restrict__ Wt,
        ushort* __restrict__ Y,
        const int* __restrict__ esrc,
        const int* __restrict__ edst,
        const float* __restrict__ ew,
        uint2* __restrict__ seg,
        int* __restrict__ cntAB) {
    __shared__ ushort Wlds[DIM * WLDS_STRIDE];   // 34816 B
    __shared__ int lcnt[NBUCK];                  // 3128 B
    int t = threadIdx.x;
    int b = blockIdx.x;

    // ---- phase A-1: independent coalesced edge loads ----
    int e0 = b * EPB + t;
    int e1 = e0 + 512, e2 = e0 + 1024;
    bool v0 = e0 < N_EDGES, v1 = e1 < N_EDGES, v2 = e2 < N_EDGES;
    int d0 = v0 ? edst[e0] : 0;
    int d1 = v1 ? edst[e1] : 0;
    int d2 = v2 ? edst[e2] : 0;
    unsigned u0 = v0 ? ((unsigned)esrc[e0] |
        ((unsigned)__bfloat16_as_ushort(__float2bfloat16(ew[e0])) << 16)) : 0u;
    unsigned u1 = v1 ? ((unsigned)esrc[e1] |
        ((unsigned)__bfloat16_as_ushort(__float2bfloat16(ew[e1])) << 16)) : 0u;
    unsigned u2 = v2 ? ((unsigned)esrc[e2] |
        ((unsigned)__bfloat16_as_ushort(__float2bfloat16(ew[e2])) << 16)) : 0u;

    for (int i = t; i < NBUCK; i += 512) lcnt[i] = 0;

    // ---- gemm: stage W into LDS ----
#pragma unroll
    for (int i = 0; i < 4; ++i) {
        int gg = t + 512 * i;
        int n = gg >> 4, c = gg & 15;
        *(uint4*)&Wlds[n * WLDS_STRIDE + c * 8] = ((const uint4*)Wt)[gg];
    }

    __syncthreads();

    // ---- phase A-2: LDS-counter appends to block-private cells ----
    if (v0) {
        int pos = atomicAdd(&lcnt[d0 >> 6], 1);
        if (pos < SEGB)
            seg[((size_t)b * NBUCK + (d0 >> 6)) * SEGB + pos] =
                make_uint2(u0, (unsigned)(d0 & 63));
    }
    if (v1) {
        int pos = atomicAdd(&lcnt[d1 >> 6], 1);
        if (pos < SEGB)
            seg[((size_t)b * NBUCK + (d1 >> 6)) * SEGB + pos] =
                make_uint2(u1, (unsigned)(d1 & 63));
    }
    if (v2) {
        int pos = atomicAdd(&lcnt[d2 >> 6], 1);
        if (pos < SEGB)
            seg[((size_t)b * NBUCK + (d2 >> 6)) * SEGB + pos] =
                make_uint2(u2, (unsigned)(d2 & 63));
    }

    // ---- gemm body (verbatim r16/r18) ----
    int w = t >> 6, l = t & 63;
    int wr = b * 128 + w * 16;
    int m = l & 15, q = l >> 4;
    int rowA = wr + m;
    if (rowA >= N_NODES) rowA = N_NODES - 1;
    const float* xp = X + (size_t)rowA * DIM + q * 8;

    floatx4 acc[8];
#pragma unroll
    for (int ct = 0; ct < 8; ++ct)
        acc[ct] = (floatx4){0.f, 0.f, 0.f, 0.f};

    const ushort* wl = &Wlds[m * WLDS_STRIDE + q * 8];
#pragma unroll
    for (int kk = 0; kk < 4; ++kk) {
        float4 x0 = *(const float4*)(xp + kk * 32);
        float4 x1 = *(const float4*)(xp + kk * 32 + 4);
        bf16x8 xf;
        xf[0] = (short)__bfloat16_as_ushort(__float2bfloat16(x0.x));
        xf[1] = (short)__bfloat16_as_ushort(__float2bfloat16(x0.y));
        xf[2] = (short)__bfloat16_as_ushort(__float2bfloat16(x0.z));
        xf[3] = (short)__bfloat16_as_ushort(__float2bfloat16(x0.w));
        xf[4] = (short)__bfloat16_as_ushort(__float2bfloat16(x1.x));
        xf[5] = (short)__bfloat16_as_ushort(__float2bfloat16(x1.y));
        xf[6] = (short)__bfloat16_as_ushort(__float2bfloat16(x1.z));
        xf[7] = (short)__bfloat16_as_ushort(__float2bfloat16(x1.w));
#pragma unroll
        for (int ct = 0; ct < 8; ++ct) {
            bf16x8 wf = *(const bf16x8*)(wl + (size_t)(ct * 16) * WLDS_STRIDE + kk * 32);
            acc[ct] = __builtin_amdgcn_mfma_f32_16x16x32_bf16(wf, xf, acc[ct], 0, 0, 0);
        }
    }

    // ---- gemm: Y stores ----
    int row = wr + m;
    if (row < N_NODES) {
        ushort* yp = Y + (size_t)row * DIM + q * 4;
#pragma unroll
        for (int ct = 0; ct < 8; ++ct) {
            ushort4 o;
            o.x = __bfloat16_as_ushort(__float2bfloat16(acc[ct][0]));
            o.y = __bfloat16_as_ushort(__float2bfloat16(acc[ct][1]));
            o.z = __bfloat16_as_ushort(__float2bfloat16(acc[ct][2]));
            o.w = __bfloat16_as_ushort(__float2bfloat16(acc[ct][3]));
            *(ushort4*)(yp + ct * 16) = o;
        }
    }

    // ---- phase A-3: publish cell counts ([bucket][block] layout) ----
    __syncthreads();
    for (int i = t; i < NBUCK; i += 512)
        cntAB[(size_t)i * GEMM_BLOCKS + b] = lcnt[i];
}

// ---------------- merged binslot + gather: one block per 64-node bucket ------
__device__ __forceinline__ float bf_lo(unsigned u) {
    return __uint_as_float(u << 16);
}
__device__ __forceinline__ float bf_hi(unsigned u) {
    return __uint_as_float(u & 0xFFFF0000u);
}

#define ACC8(A, W, Y4)                                        \
    A[0] += (W) * bf_lo((Y4).x); A[1] += (W) * bf_hi((Y4).x); \
    A[2] += (W) * bf_lo((Y4).y); A[3] += (W) * bf_hi((Y4).y); \
    A[4] += (W) * bf_lo((Y4).z); A[5] += (W) * bf_hi((Y4).z); \
    A[6] += (W) * bf_lo((Y4).w); A[7] += (W) * bf_hi((Y4).w);

__global__ __launch_bounds__(512) void k_bingather(
        const ushort* __restrict__ Y,
        const int* __restrict__ cntAB,
        const uint2* __restrict__ seg,
        const float* __restrict__ bias,
        float* __restrict__ out) {
    __shared__ int lcounts[GEMM_BLOCKS];        // 391 ints
    __shared__ int lcnt2[BNODES];
    __shared__ unsigned lslot[BNODES][CAPL];    // 10240 B
    int bucket = blockIdx.x;
    int t = threadIdx.x;

    // coalesced row read of this bucket's 391 cell counts
    for (int i = t; i < GEMM_BLOCKS; i += 512)
        lcounts[i] = cntAB[(size_t)bucket * GEMM_BLOCKS + i];
    if (t < BNODES) lcnt2[t] = 0;
    __syncthreads();

    // bin: one cell per thread
    if (t < GEMM_BLOCKS) {
        int count = lcounts[t];
        if (count > SEGB) count = SEGB;
        const uint2* cell = seg + ((size_t)t * NBUCK + bucket) * SEGB;
        for (int i = 0; i < count; ++i) {
            uint2 en = cell[i];
            int ln = (int)en.y;
            int pos = atomicAdd(&lcnt2[ln], 1);
            if (pos < CAPL) lslot[ln][pos] = en.x;
        }
    }
    __syncthreads();

    // gather: 32 node-groups of 16 lanes, 2 iterations cover 64 nodes
    int c = (t & 15) * 8;
    float4 bA = *(const float4*)(bias + c);
    float4 bB = *(const float4*)(bias + c + 4);
#pragma unroll
    for (int iter = 0; iter < 2; ++iter) {
        int ln = iter * 32 + (t >> 4);
        int node = bucket * BNODES + ln;
        if (node >= N_NODES) continue;
        int deg = lcnt2[ln];
        if (deg > CAPL) deg = CAPL;

        float a0[8], a1[8];
#pragma unroll
        for (int k = 0; k < 8; ++k) { a0[k] = 0.f; a1[k] = 0.f; }

        for (int base = 0; base < deg; base += 16) {
            int   idx[16];
            float wgt[16];
#pragma unroll
            for (int i = 0; i < 16; ++i) {
                int j = base + i;
                unsigned sv = (j < deg) ? lslot[ln][j] : 0u;
                idx[i] = (int)(sv & 0xFFFFu);
                wgt[i] = bf_hi(sv);
            }
            uint4 y[16];
#pragma unroll
            for (int i = 0; i < 16; ++i)
                y[i] = *(const uint4*)(Y + (size_t)idx[i] * DIM + c);
#pragma unroll
            for (int i = 0; i < 16; i += 2) {
                ACC8(a0, wgt[i], y[i]);
                ACC8(a1, wgt[i + 1], y[i + 1]);
            }
        }

        float* op = out + (size_t)node * DIM + c;
        floatx4 o0 = {a0[0] + a1[0] + bA.x, a0[1] + a1[1] + bA.y,
                      a0[2] + a1[2] + bA.z, a0[3] + a1[3] + bA.w};
        floatx4 o1 = {a0[4] + a1[4] + bB.x, a0[5] + a1[5] + bB.y,
                      a0[6] + a1[6] + bB.z, a0[7] + a1[7] + bB.w};
        __builtin_nontemporal_store(o0, (floatx4*)(op + 0));
        __builtin_nontemporal_store(o1, (floatx4*)(op + 4));
    }
}

// ---------------- fallback path kernels (ws too small) ----------------
__global__ void zero_ws(float4* __restrict__ p, int n4) {
    int i = blockIdx.x * blockDim.x + threadIdx.x;
    if (i < n4) p[i] = make_float4(0.f, 0.f, 0.f, 0.f);
}

__global__ __launch_bounds__(256) void scatter_edges(
        const float* __restrict__ x,
        const float* __restrict__ ew,
        const int* __restrict__ esrc,
        const int* __restrict__ edst,
        float* __restrict__ agg) {
    long long t = (long long)blockIdx.x * blockDim.x + threadIdx.x;
    int e = (int)(t >> 5);
    if (e >= N_EDGES) return;
    int d4 = ((int)t & 31) * 4;
    int s = esrc[e];
    int d = edst[e];
    float w = ew[e];
    float4 xv = *(const float4*)(x + (size_t)s * DIM + d4);
    float* ap = agg + (size_t)d * DIM + d4;
    atomicAdd(ap + 0, w * xv.x);
    atomicAdd(ap + 1, w * xv.y);
    atomicAdd(ap + 2, w * xv.z);
    atomicAdd(ap + 3, w * xv.w);
}

__global__ __launch_bounds__(256) void gemm_f32_bias(
        const float* __restrict__ A,
        const float* __restrict__ W,
        const float* __restrict__ bias,
        float* __restrict__ out) {
    __shared__ float Ws[DIM][DIM];
    int tid = threadIdx.x;
    const float4* W4 = (const float4*)W;
    float4* Ws4 = (float4*)&Ws[0][0];
#pragma unroll
    for (int i = 0; i < 16; ++i) Ws4[tid + 256 * i] = W4[tid + 256 * i];
    __syncthreads();

    int row0 = blockIdx.x * 64 + (tid >> 5) * 8;
    int cg = (tid & 31) * 4;
    float4 b = *(const float4*)(bias + cg);
    float acc[8][4];
#pragma unroll
    for (int i = 0; i < 8; ++i) {
        acc[i][0] = b.x; acc[i][1] = b.y; acc[i][2] = b.z; acc[i][3] = b.w;
    }
    int rload[8];
#pragma unroll
    for (int i = 0; i < 8; ++i) {
        int r = row0 + i;
        rload[i] = (r < N_NODES) ? r : (N_NODES - 1);
    }
    for (int kt = 0; kt < 32; ++kt) {
        float4 xr[8];
#pragma unroll
        for (int i = 0; i < 8; ++i)
            xr[i] = *(const float4*)(A + (size_t)rload[i] * DIM + kt * 4);
        float4 wr[4];
#pragma unroll
        for (int j = 0; j < 4; ++j)
            wr[j] = *(const float4*)&Ws[kt * 4 + j][cg];
#pragma unroll
        for (int i = 0; i < 8; ++i) {
            acc[i][0] += xr[i].x * wr[0].x + xr[i].y * wr[1].x + xr[i].z * wr[2].x + xr[i].w * wr[3].x;
            acc[i][1] += xr[i].x * wr[0].y + xr[i].y * wr[1].y + xr[i].z * wr[2].y + xr[i].w * wr[3].y;
            acc[i][2] += xr[i].x * wr[0].z + xr[i].y * wr[1].z + xr[i].z * wr[2].z + xr[i].w * wr[3].z;
            acc[i][3] += xr[i].x * wr[0].w + xr[i].y * wr[1].w + xr[i].z * wr[2].w + xr[i].w * wr[3].w;
        }
    }
#pragma unroll
    for (int i = 0; i < 8; ++i) {
        int row = row0 + i;
        if (row >= N_NODES) break;
        *(float4*)(out + (size_t)row * DIM + cg) =
            make_float4(acc[i][0], acc[i][1], acc[i][2], acc[i][3]);
    }
}

extern "C" void kernel_launch(void* const* d_in, const int* in_sizes, int n_in,
                              void* d_out, int out_size, void* d_ws, size_t ws_size,
                              hipStream_t stream) {
    const float* batch_x     = (const float*)d_in[0];
    const float* edge_weight = (const float*)d_in[1];
    const float* weight      = (const float*)d_in[2];
    const float* bias        = (const float*)d_in[3];
    const int*   edge_src    = (const int*)d_in[4];
    const int*   edge_dst    = (const int*)d_in[5];
    float* out = (float*)d_out;

    auto align256 = [](size_t x) { return (x + 255) & ~(size_t)255; };
    char* ws = (char*)d_ws;

    size_t oY    = 0;                                                            // 12.8 MB
    size_t oWt   = align256(oY + (size_t)N_NODES * DIM * sizeof(ushort));        // 32 KB
    size_t oCAB  = align256(oWt + (size_t)DIM * DIM * sizeof(ushort));           // 1.22 MB
    size_t oSeg  = align256(oCAB + (size_t)NBUCK * GEMM_BLOCKS * sizeof(int));   // 39.1 MB
    size_t needed = oSeg + (size_t)GEMM_BLOCKS * NBUCK * SEGB * sizeof(uint2);

    if (ws_size >= needed) {
        ushort*   Y     = (ushort*)(ws + oY);
        ushort*   Wt    = (ushort*)(ws + oWt);
        int*      cntAB = (int*)(ws + oCAB);
        uint2*    seg   = (uint2*)(ws + oSeg);

        // 1) prep W (transpose+bf16)
        k_prep<<<16, 256, 0, stream>>>(weight, Wt);

        // 2) fused gemm + phase-A bucketing (64-node buckets)
        k_gemm_fill<<<GEMM_BLOCKS, 512, 0, stream>>>(
            batch_x, Wt, Y, edge_src, edge_dst, edge_weight, seg, cntAB);

        // 3) merged binslot + gather (+bias, NT out stores)
        k_bingather<<<NBUCK, 512, 0, stream>>>(Y, cntAB, seg, bias, out);
    } else {
        // fallback: atomic path (needs 25.6 MB)
        float* agg = (float*)d_ws;
        int n4 = N_NODES * DIM / 4;
        zero_ws<<<(n4 + 255) / 256, 256, 0, stream>>>((float4*)agg, n4);
        long long threads = (long long)N_EDGES * 32;
        scatter_edges<<<(int)((threads + 255) / 256), 256, 0, stream>>>(
            batch_x, edge_weight, edge_src, edge_dst, agg);
        gemm_f32_bias<<<(N_NODES + 63) / 64, 256, 0, stream>>>(
            agg, weight, bias, out);
    }
}

// Round 26
// 58.642 us; speedup vs baseline: 1.1155x; 1.1155x over previous
//
#include <hip/hip_runtime.h>
#include <hip/hip_bf16.h>

#define N_NODES 50000
#define N_EDGES 600000
#define DIM 128
#define CAP 64            // total slots per node (A+B)
#define CAP_A 16
#define CAP_B 48
#define NBUCK 196         // coarse buckets (dst>>8), 256 nodes each
#define NPAD (NBUCK * 256)// 50176 padded nodes
#define SEGB 32           // per-(block,bucket) cell capacity; Poisson(7.8)
#define WLDS_STRIDE 136
#define EPB 1536          // edges per gemm block (512 thr x 3); 391*1536 >= 600k
#define GEMM_BLOCKS 391

typedef __attribute__((ext_vector_type(8))) short bf16x8;
typedef __attribute__((ext_vector_type(4))) float floatx4;

// ---------------- prep: Wt[n][k] = bf16(W[k][n]) (verbatim r22/r24) ----------
__global__ __launch_bounds__(256) void k_prep(const float* __restrict__ W,
                                              ushort* __restrict__ Wt) {
    int idx = (blockIdx.x * 256 + threadIdx.x) * 4;
    float4 v = *(const float4*)(W + idx);
    int k = idx >> 7, n = idx & 127;
    Wt[(size_t)(n + 0) * DIM + k] = __bfloat16_as_ushort(__float2bfloat16(v.x));
    Wt[(size_t)(n + 1) * DIM + k] = __bfloat16_as_ushort(__float2bfloat16(v.y));
    Wt[(size_t)(n + 2) * DIM + k] = __bfloat16_as_ushort(__float2bfloat16(v.z));
    Wt[(size_t)(n + 3) * DIM + k] = __bfloat16_as_ushort(__float2bfloat16(v.w));
}

// ---------------- fused MFMA GEMM + phase-A bucketing (r24; cntAB transposed)
__global__ __launch_bounds__(512) void k_gemm_fill(
        const float* __restrict__ X,
        const ushort* __restrict__ Wt,
        ushort* __restrict__ Y,
        const int* __restrict__ esrc,
        const int* __restrict__ edst,
        const float* __restrict__ ew,
        uint2* __restrict__ seg,
        int* __restrict__ cntAB) {
    __shared__ ushort Wlds[DIM * WLDS_STRIDE];   // 34816 B
    __shared__ int lcnt[NBUCK];
    int t = threadIdx.x;
    int b = blockIdx.x;

    // ---- phase A-1: independent coalesced edge loads ----
    int e0 = b * EPB + t;
    int e1 = e0 + 512, e2 = e0 + 1024;
    bool v0 = e0 < N_EDGES, v1 = e1 < N_EDGES, v2 = e2 < N_EDGES;
    int d0 = v0 ? edst[e0] : 0;
    int d1 = v1 ? edst[e1] : 0;
    int d2 = v2 ? edst[e2] : 0;
    unsigned u0 = v0 ? ((unsigned)esrc[e0] |
        ((unsigned)__bfloat16_as_ushort(__float2bfloat16(ew[e0])) << 16)) : 0u;
    unsigned u1 = v1 ? ((unsigned)esrc[e1] |
        ((unsigned)__bfloat16_as_ushort(__float2bfloat16(ew[e1])) << 16)) : 0u;
    unsigned u2 = v2 ? ((unsigned)esrc[e2] |
        ((unsigned)__bfloat16_as_ushort(__float2bfloat16(ew[e2])) << 16)) : 0u;

    if (t < NBUCK) lcnt[t] = 0;

    // ---- gemm: stage W into LDS ----
#pragma unroll
    for (int i = 0; i < 4; ++i) {
        int gg = t + 512 * i;
        int n = gg >> 4, c = gg & 15;
        *(uint4*)&Wlds[n * WLDS_STRIDE + c * 8] = ((const uint4*)Wt)[gg];
    }

    __syncthreads();

    // ---- phase A-2: LDS-counter appends to block-private cells ----
    if (v0) {
        int pos = atomicAdd(&lcnt[d0 >> 8], 1);
        if (pos < SEGB)
            seg[((size_t)b * NBUCK + (d0 >> 8)) * SEGB + pos] =
                make_uint2(u0, (unsigned)(d0 & 255));
    }
    if (v1) {
        int pos = atomicAdd(&lcnt[d1 >> 8], 1);
        if (pos < SEGB)
            seg[((size_t)b * NBUCK + (d1 >> 8)) * SEGB + pos] =
                make_uint2(u1, (unsigned)(d1 & 255));
    }
    if (v2) {
        int pos = atomicAdd(&lcnt[d2 >> 8], 1);
        if (pos < SEGB)
            seg[((size_t)b * NBUCK + (d2 >> 8)) * SEGB + pos] =
                make_uint2(u2, (unsigned)(d2 & 255));
    }

    // ---- gemm body (verbatim r16/r18) ----
    int w = t >> 6, l = t & 63;
    int wr = b * 128 + w * 16;
    int m = l & 15, q = l >> 4;
    int rowA = wr + m;
    if (rowA >= N_NODES) rowA = N_NODES - 1;
    const float* xp = X + (size_t)rowA * DIM + q * 8;

    floatx4 acc[8];
#pragma unroll
    for (int ct = 0; ct < 8; ++ct)
        acc[ct] = (floatx4){0.f, 0.f, 0.f, 0.f};

    const ushort* wl = &Wlds[m * WLDS_STRIDE + q * 8];
#pragma unroll
    for (int kk = 0; kk < 4; ++kk) {
        float4 x0 = *(const float4*)(xp + kk * 32);
        float4 x1 = *(const float4*)(xp + kk * 32 + 4);
        bf16x8 xf;
        xf[0] = (short)__bfloat16_as_ushort(__float2bfloat16(x0.x));
        xf[1] = (short)__bfloat16_as_ushort(__float2bfloat16(x0.y));
        xf[2] = (short)__bfloat16_as_ushort(__float2bfloat16(x0.z));
        xf[3] = (short)__bfloat16_as_ushort(__float2bfloat16(x0.w));
        xf[4] = (short)__bfloat16_as_ushort(__float2bfloat16(x1.x));
        xf[5] = (short)__bfloat16_as_ushort(__float2bfloat16(x1.y));
        xf[6] = (short)__bfloat16_as_ushort(__float2bfloat16(x1.z));
        xf[7] = (short)__bfloat16_as_ushort(__float2bfloat16(x1.w));
#pragma unroll
        for (int ct = 0; ct < 8; ++ct) {
            bf16x8 wf = *(const bf16x8*)(wl + (size_t)(ct * 16) * WLDS_STRIDE + kk * 32);
            acc[ct] = __builtin_amdgcn_mfma_f32_16x16x32_bf16(wf, xf, acc[ct], 0, 0, 0);
        }
    }

    // ---- gemm: Y stores ----
    int row = wr + m;
    if (row < N_NODES) {
        ushort* yp = Y + (size_t)row * DIM + q * 4;
#pragma unroll
        for (int ct = 0; ct < 8; ++ct) {
            ushort4 o;
            o.x = __bfloat16_as_ushort(__float2bfloat16(acc[ct][0]));
            o.y = __bfloat16_as_ushort(__float2bfloat16(acc[ct][1]));
            o.z = __bfloat16_as_ushort(__float2bfloat16(acc[ct][2]));
            o.w = __bfloat16_as_ushort(__float2bfloat16(acc[ct][3]));
            *(ushort4*)(yp + ct * 16) = o;
        }
    }

    // ---- phase A-3: publish cell counts ([bucket][block] layout; scattered
    // fire-and-forget writes, hidden under kernel tail) ----
    __syncthreads();
    if (t < NBUCK) cntAB[(size_t)t * GEMM_BLOCKS + b] = lcnt[t];
}

// ---------------- phase B: bucket -> per-node slots (r24; coalesced cnt read)
__global__ __launch_bounds__(512) void k_binslot(
        const uint2* __restrict__ seg,
        const int* __restrict__ cntAB,
        int* __restrict__ cnt,
        unsigned* __restrict__ slotA,
        unsigned* __restrict__ slotB) {
    __shared__ int lcnt[256];
    __shared__ unsigned lslot[256][CAP_A];   // 16 KB
    int bucket = blockIdx.x;
    int t = threadIdx.x;
    if (t < 256) lcnt[t] = 0;
    __syncthreads();

    if (t < GEMM_BLOCKS) {
        int count = cntAB[(size_t)bucket * GEMM_BLOCKS + t];   // coalesced row
        if (count > SEGB) count = SEGB;
        const uint2* cell = seg + ((size_t)t * NBUCK + bucket) * SEGB;
        for (int i = 0; i < count; ++i) {
            uint2 en = cell[i];
            int ln = (int)en.y;
            int pos = atomicAdd(&lcnt[ln], 1);
            if (pos < CAP_A)
                lslot[ln][pos] = en.x;
            else if (pos < CAP)
                slotB[(size_t)(bucket * 256 + ln) * CAP_B + (pos - CAP_A)] = en.x;
        }
    }
    __syncthreads();

    if (t < 256) cnt[bucket * 256 + t] = lcnt[t];
    // slotA: 256 nodes x 4 uint4 = 1024 uint4, 2 per thread, coalesced
    uint4* ap = (uint4*)(slotA + (size_t)bucket * 256 * CAP_A);
    const uint4* ls = (const uint4*)&lslot[0][0];
#pragma unroll
    for (int i = 0; i < 2; ++i)
        ap[t + 512 * i] = ls[t + 512 * i];
}

// ---------------- gather (verbatim r24; nontemporal out stores) --------------
__device__ __forceinline__ float bf_lo(unsigned u) {
    return __uint_as_float(u << 16);
}
__device__ __forceinline__ float bf_hi(unsigned u) {
    return __uint_as_float(u & 0xFFFF0000u);
}

#define ACC8(A, W, Y4)                                        \
    A[0] += (W) * bf_lo((Y4).x); A[1] += (W) * bf_hi((Y4).x); \
    A[2] += (W) * bf_lo((Y4).y); A[3] += (W) * bf_hi((Y4).y); \
    A[4] += (W) * bf_lo((Y4).z); A[5] += (W) * bf_hi((Y4).z); \
    A[6] += (W) * bf_lo((Y4).w); A[7] += (W) * bf_hi((Y4).w);

__device__ __forceinline__ void chunk16(const uint4* __restrict__ s4, int soff,
                                        int base, int deg,
                                        const ushort* __restrict__ Y, int c,
                                        float* a0, float* a1) {
    int   idx[16];
    float wgt[16];
#pragma unroll
    for (int i = 0; i < 4; ++i) {
        uint4 sv = s4[soff + i];
        int j = base + 4 * i;
        idx[4 * i + 0] = (j + 0 < deg) ? (int)(sv.x & 0xFFFFu) : 0;
        wgt[4 * i + 0] = (j + 0 < deg) ? bf_hi(sv.x) : 0.f;
        idx[4 * i + 1] = (j + 1 < deg) ? (int)(sv.y & 0xFFFFu) : 0;
        wgt[4 * i + 1] = (j + 1 < deg) ? bf_hi(sv.y) : 0.f;
        idx[4 * i + 2] = (j + 2 < deg) ? (int)(sv.z & 0xFFFFu) : 0;
        wgt[4 * i + 2] = (j + 2 < deg) ? bf_hi(sv.z) : 0.f;
        idx[4 * i + 3] = (j + 3 < deg) ? (int)(sv.w & 0xFFFFu) : 0;
        wgt[4 * i + 3] = (j + 3 < deg) ? bf_hi(sv.w) : 0.f;
    }
    uint4 y[16];
#pragma unroll
    for (int i = 0; i < 16; ++i)
        y[i] = *(const uint4*)(Y + (size_t)idx[i] * DIM + c);
#pragma unroll
    for (int i = 0; i < 16; i += 2) {
        ACC8(a0, wgt[i], y[i]);
        ACC8(a1, wgt[i + 1], y[i + 1]);
    }
}

__global__ __launch_bounds__(256) void k_gather_ab(
        const ushort* __restrict__ Y,
        const int* __restrict__ cnt,
        const unsigned* __restrict__ slotA,
        const unsigned* __restrict__ slotB,
        const float* __restrict__ bias,
        float* __restrict__ out) {
    int node = blockIdx.x * 16 + (threadIdx.x >> 4);
    if (node >= N_NODES) return;
    int c = (threadIdx.x & 15) * 8;
    int deg = cnt[node];
    if (deg > CAP) deg = CAP;

    float a0[8], a1[8];
#pragma unroll
    for (int k = 0; k < 8; ++k) { a0[k] = 0.f; a1[k] = 0.f; }

    const uint4* a4 = (const uint4*)(slotA + (size_t)node * CAP_A);
    chunk16(a4, 0, 0, deg, Y, c, a0, a1);

    if (deg > CAP_A) {
        const uint4* b4 = (const uint4*)(slotB + (size_t)node * CAP_B);
        for (int base = CAP_A; base < deg; base += 16)
            chunk16(b4, (base - CAP_A) >> 2, base, deg, Y, c, a0, a1);
    }

    float4 bA = *(const float4*)(bias + c);
    float4 bB = *(const float4*)(bias + c + 4);
    float* op = out + (size_t)node * DIM + c;
    floatx4 o0 = {a0[0] + a1[0] + bA.x, a0[1] + a1[1] + bA.y,
                  a0[2] + a1[2] + bA.z, a0[3] + a1[3] + bA.w};
    floatx4 o1 = {a0[4] + a1[4] + bB.x, a0[5] + a1[5] + bB.y,
                  a0[6] + a1[6] + bB.z, a0[7] + a1[7] + bB.w};
    __builtin_nontemporal_store(o0, (floatx4*)(op + 0));
    __builtin_nontemporal_store(o1, (floatx4*)(op + 4));
}

// ---------------- fallback path kernels (ws too small) ----------------
__global__ void zero_ws(float4* __restrict__ p, int n4) {
    int i = blockIdx.x * blockDim.x + threadIdx.x;
    if (i < n4) p[i] = make_float4(0.f, 0.f, 0.f, 0.f);
}

__global__ __launch_bounds__(256) void scatter_edges(
        const float* __restrict__ x,
        const float* __restrict__ ew,
        const int* __restrict__ esrc,
        const int* __restrict__ edst,
        float* __restrict__ agg) {
    long long t = (long long)blockIdx.x * blockDim.x + threadIdx.x;
    int e = (int)(t >> 5);
    if (e >= N_EDGES) return;
    int d4 = ((int)t & 31) * 4;
    int s = esrc[e];
    int d = edst[e];
    float w = ew[e];
    float4 xv = *(const float4*)(x + (size_t)s * DIM + d4);
    float* ap = agg + (size_t)d * DIM + d4;
    atomicAdd(ap + 0, w * xv.x);
    atomicAdd(ap + 1, w * xv.y);
    atomicAdd(ap + 2, w * xv.z);
    atomicAdd(ap + 3, w * xv.w);
}

__global__ __launch_bounds__(256) void gemm_f32_bias(
        const float* __restrict__ A,
        const float* __restrict__ W,
        const float* __restrict__ bias,
        float* __restrict__ out) {
    __shared__ float Ws[DIM][DIM];
    int tid = threadIdx.x;
    const float4* W4 = (const float4*)W;
    float4* Ws4 = (float4*)&Ws[0][0];
#pragma unroll
    for (int i = 0; i < 16; ++i) Ws4[tid + 256 * i] = W4[tid + 256 * i];
    __syncthreads();

    int row0 = blockIdx.x * 64 + (tid >> 5) * 8;
    int cg = (tid & 31) * 4;
    float4 b = *(const float4*)(bias + cg);
    float acc[8][4];
#pragma unroll
    for (int i = 0; i < 8; ++i) {
        acc[i][0] = b.x; acc[i][1] = b.y; acc[i][2] = b.z; acc[i][3] = b.w;
    }
    int rload[8];
#pragma unroll
    for (int i = 0; i < 8; ++i) {
        int r = row0 + i;
        rload[i] = (r < N_NODES) ? r : (N_NODES - 1);
    }
    for (int kt = 0; kt < 32; ++kt) {
        float4 xr[8];
#pragma unroll
        for (int i = 0; i < 8; ++i)
            xr[i] = *(const float4*)(A + (size_t)rload[i] * DIM + kt * 4);
        float4 wr[4];
#pragma unroll
        for (int j = 0; j < 4; ++j)
            wr[j] = *(const float4*)&Ws[kt * 4 + j][cg];
#pragma unroll
        for (int i = 0; i < 8; ++i) {
            acc[i][0] += xr[i].x * wr[0].x + xr[i].y * wr[1].x + xr[i].z * wr[2].x + xr[i].w * wr[3].x;
            acc[i][1] += xr[i].x * wr[0].y + xr[i].y * wr[1].y + xr[i].z * wr[2].y + xr[i].w * wr[3].y;
            acc[i][2] += xr[i].x * wr[0].z + xr[i].y * wr[1].z + xr[i].z * wr[2].z + xr[i].w * wr[3].z;
            acc[i][3] += xr[i].x * wr[0].w + xr[i].y * wr[1].w + xr[i].z * wr[2].w + xr[i].w * wr[3].w;
        }
    }
#pragma unroll
    for (int i = 0; i < 8; ++i) {
        int row = row0 + i;
        if (row >= N_NODES) break;
        *(float4*)(out + (size_t)row * DIM + cg) =
            make_float4(acc[i][0], acc[i][1], acc[i][2], acc[i][3]);
    }
}

extern "C" void kernel_launch(void* const* d_in, const int* in_sizes, int n_in,
                              void* d_out, int out_size, void* d_ws, size_t ws_size,
                              hipStream_t stream) {
    const float* batch_x     = (const float*)d_in[0];
    const float* edge_weight = (const float*)d_in[1];
    const float* weight      = (const float*)d_in[2];
    const float* bias        = (const float*)d_in[3];
    const int*   edge_src    = (const int*)d_in[4];
    const int*   edge_dst    = (const int*)d_in[5];
    float* out = (float*)d_out;

    auto align256 = [](size_t x) { return (x + 255) & ~(size_t)255; };
    char* ws = (char*)d_ws;

    size_t oY    = 0;                                                            // 12.8 MB
    size_t oCnt  = align256(oY + (size_t)N_NODES * DIM * sizeof(ushort));        // 200 KB
    size_t oA    = align256(oCnt + (size_t)NPAD * sizeof(int));                  // 3.2 MB
    size_t oB    = align256(oA + (size_t)NPAD * CAP_A * sizeof(unsigned));       // 9.6 MB
    size_t oWt   = align256(oB + (size_t)NPAD * CAP_B * sizeof(unsigned));       // 32 KB
    size_t oCAB  = align256(oWt + (size_t)DIM * DIM * sizeof(ushort));           // 306 KB
    size_t oSeg  = align256(oCAB + (size_t)GEMM_BLOCKS * NBUCK * sizeof(int));   // 19.6 MB
    size_t needed = oSeg + (size_t)GEMM_BLOCKS * NBUCK * SEGB * sizeof(uint2);

    if (ws_size >= needed) {
        ushort*   Y     = (ushort*)(ws + oY);
        int*      cnt   = (int*)(ws + oCnt);
        unsigned* slotA = (unsigned*)(ws + oA);
        unsigned* slotB = (unsigned*)(ws + oB);
        ushort*   Wt    = (ushort*)(ws + oWt);
        int*      cntAB = (int*)(ws + oCAB);
        uint2*    seg   = (uint2*)(ws + oSeg);

        // 1) prep W (transpose+bf16)
        k_prep<<<16, 256, 0, stream>>>(weight, Wt);

        // 2) fused gemm + phase-A bucketing (LDS counters, private cells)
        k_gemm_fill<<<GEMM_BLOCKS, 512, 0, stream>>>(
            batch_x, Wt, Y, edge_src, edge_dst, edge_weight, seg, cntAB);

        // 3) phase B: buckets -> per-node slots (coalesced cnt read)
        k_binslot<<<NBUCK, 512, 0, stream>>>(seg, cntAB, cnt, slotA, slotB);

        // 4) gather + bias (nontemporal out stores)
        k_gather_ab<<<(N_NODES + 15) / 16, 256, 0, stream>>>(
            Y, cnt, slotA, slotB, bias, out);
    } else {
        // fallback: atomic path (needs 25.6 MB)
        float* agg = (float*)d_ws;
        int n4 = N_NODES * DIM / 4;
        zero_ws<<<(n4 + 255) / 256, 256, 0, stream>>>((float4*)agg, n4);
        long long threads = (long long)N_EDGES * 32;
        scatter_edges<<<(int)((threads + 255) / 256), 256, 0, stream>>>(
            batch_x, edge_weight, edge_src, edge_dst, agg);
        gemm_f32_bias<<<(N_NODES + 63) / 64, 256, 0, stream>>>(
            agg, weight, bias, out);
    }
}

// Round 27
// 56.290 us; speedup vs baseline: 1.1622x; 1.0418x over previous
//
#include <hip/hip_runtime.h>
#include <hip/hip_bf16.h>

#define N_NODES 50000
#define N_EDGES 600000
#define DIM 128
#define CAP 64            // total slots per node (A+B)
#define CAP_A 16
#define CAP_B 48
#define NBUCK 196         // coarse buckets (dst>>8), 256 nodes each
#define NPAD (NBUCK * 256)// 50176 padded nodes
#define SEGB 32           // per-(block,bucket) cell capacity; Poisson(7.8)
#define WLDS_STRIDE 136
#define EPB 1536          // edges per gemm block (512 thr x 3); 391*1536 >= 600k
#define GEMM_BLOCKS 391

typedef __attribute__((ext_vector_type(8))) short bf16x8;
typedef __attribute__((ext_vector_type(4))) float floatx4;

// ---------------- fused MFMA GEMM + phase-A bucketing + inline W prep --------
// r26 body with the W transpose+convert done in-kernel (coalesced fp32 row
// reads; 4x2B scattered LDS writes, ~16-way bank alias, cost < saved dispatch).
__global__ __launch_bounds__(512) void k_gemm_fill(
        const float* __restrict__ X,
        const float* __restrict__ W,
        ushort* __restrict__ Y,
        const int* __restrict__ esrc,
        const int* __restrict__ edst,
        const float* __restrict__ ew,
        uint2* __restrict__ seg,
        int* __restrict__ cntAB) {
    __shared__ ushort Wlds[DIM * WLDS_STRIDE];   // 34816 B
    __shared__ int lcnt[NBUCK];
    int t = threadIdx.x;
    int b = blockIdx.x;

    // ---- phase A-1: independent coalesced edge loads ----
    int e0 = b * EPB + t;
    int e1 = e0 + 512, e2 = e0 + 1024;
    bool v0 = e0 < N_EDGES, v1 = e1 < N_EDGES, v2 = e2 < N_EDGES;
    int d0 = v0 ? edst[e0] : 0;
    int d1 = v1 ? edst[e1] : 0;
    int d2 = v2 ? edst[e2] : 0;
    unsigned u0 = v0 ? ((unsigned)esrc[e0] |
        ((unsigned)__bfloat16_as_ushort(__float2bfloat16(ew[e0])) << 16)) : 0u;
    unsigned u1 = v1 ? ((unsigned)esrc[e1] |
        ((unsigned)__bfloat16_as_ushort(__float2bfloat16(ew[e1])) << 16)) : 0u;
    unsigned u2 = v2 ? ((unsigned)esrc[e2] |
        ((unsigned)__bfloat16_as_ushort(__float2bfloat16(ew[e2])) << 16)) : 0u;

    if (t < NBUCK) lcnt[t] = 0;

    // ---- inline W prep: Wlds[n][k] = bf16(W[k][n]) ----
    // 4096 float4 work items; coalesced row reads, transposed 2B LDS writes.
#pragma unroll
    for (int i = 0; i < 8; ++i) {
        int g = t + 512 * i;
        int k = g >> 5, nq = g & 31;
        float4 v = *(const float4*)(W + (size_t)k * DIM + nq * 4);
        Wlds[(4 * nq + 0) * WLDS_STRIDE + k] = __bfloat16_as_ushort(__float2bfloat16(v.x));
        Wlds[(4 * nq + 1) * WLDS_STRIDE + k] = __bfloat16_as_ushort(__float2bfloat16(v.y));
        Wlds[(4 * nq + 2) * WLDS_STRIDE + k] = __bfloat16_as_ushort(__float2bfloat16(v.z));
        Wlds[(4 * nq + 3) * WLDS_STRIDE + k] = __bfloat16_as_ushort(__float2bfloat16(v.w));
    }

    __syncthreads();

    // ---- phase A-2: LDS-counter appends to block-private cells ----
    if (v0) {
        int pos = atomicAdd(&lcnt[d0 >> 8], 1);
        if (pos < SEGB)
            seg[((size_t)b * NBUCK + (d0 >> 8)) * SEGB + pos] =
                make_uint2(u0, (unsigned)(d0 & 255));
    }
    if (v1) {
        int pos = atomicAdd(&lcnt[d1 >> 8], 1);
        if (pos < SEGB)
            seg[((size_t)b * NBUCK + (d1 >> 8)) * SEGB + pos] =
                make_uint2(u1, (unsigned)(d1 & 255));
    }
    if (v2) {
        int pos = atomicAdd(&lcnt[d2 >> 8], 1);
        if (pos < SEGB)
            seg[((size_t)b * NBUCK + (d2 >> 8)) * SEGB + pos] =
                make_uint2(u2, (unsigned)(d2 & 255));
    }

    // ---- gemm body (verbatim r16/r18/r26) ----
    int w = t >> 6, l = t & 63;
    int wr = b * 128 + w * 16;
    int m = l & 15, q = l >> 4;
    int rowA = wr + m;
    if (rowA >= N_NODES) rowA = N_NODES - 1;
    const float* xp = X + (size_t)rowA * DIM + q * 8;

    floatx4 acc[8];
#pragma unroll
    for (int ct = 0; ct < 8; ++ct)
        acc[ct] = (floatx4){0.f, 0.f, 0.f, 0.f};

    const ushort* wl = &Wlds[m * WLDS_STRIDE + q * 8];
#pragma unroll
    for (int kk = 0; kk < 4; ++kk) {
        float4 x0 = *(const float4*)(xp + kk * 32);
        float4 x1 = *(const float4*)(xp + kk * 32 + 4);
        bf16x8 xf;
        xf[0] = (short)__bfloat16_as_ushort(__float2bfloat16(x0.x));
        xf[1] = (short)__bfloat16_as_ushort(__float2bfloat16(x0.y));
        xf[2] = (short)__bfloat16_as_ushort(__float2bfloat16(x0.z));
        xf[3] = (short)__bfloat16_as_ushort(__float2bfloat16(x0.w));
        xf[4] = (short)__bfloat16_as_ushort(__float2bfloat16(x1.x));
        xf[5] = (short)__bfloat16_as_ushort(__float2bfloat16(x1.y));
        xf[6] = (short)__bfloat16_as_ushort(__float2bfloat16(x1.z));
        xf[7] = (short)__bfloat16_as_ushort(__float2bfloat16(x1.w));
#pragma unroll
        for (int ct = 0; ct < 8; ++ct) {
            bf16x8 wf = *(const bf16x8*)(wl + (size_t)(ct * 16) * WLDS_STRIDE + kk * 32);
            acc[ct] = __builtin_amdgcn_mfma_f32_16x16x32_bf16(wf, xf, acc[ct], 0, 0, 0);
        }
    }

    // ---- gemm: Y stores ----
    int row = wr + m;
    if (row < N_NODES) {
        ushort* yp = Y + (size_t)row * DIM + q * 4;
#pragma unroll
        for (int ct = 0; ct < 8; ++ct) {
            ushort4 o;
            o.x = __bfloat16_as_ushort(__float2bfloat16(acc[ct][0]));
            o.y = __bfloat16_as_ushort(__float2bfloat16(acc[ct][1]));
            o.z = __bfloat16_as_ushort(__float2bfloat16(acc[ct][2]));
            o.w = __bfloat16_as_ushort(__float2bfloat16(acc[ct][3]));
            *(ushort4*)(yp + ct * 16) = o;
        }
    }

    // ---- phase A-3: publish cell counts ([bucket][block] layout) ----
    __syncthreads();
    if (t < NBUCK) cntAB[(size_t)t * GEMM_BLOCKS + b] = lcnt[t];
}

// ---------------- phase B: bucket -> per-node slots (verbatim r26) -----------
__global__ __launch_bounds__(512) void k_binslot(
        const uint2* __restrict__ seg,
        const int* __restrict__ cntAB,
        int* __restrict__ cnt,
        unsigned* __restrict__ slotA,
        unsigned* __restrict__ slotB) {
    __shared__ int lcnt[256];
    __shared__ unsigned lslot[256][CAP_A];   // 16 KB
    int bucket = blockIdx.x;
    int t = threadIdx.x;
    if (t < 256) lcnt[t] = 0;
    __syncthreads();

    if (t < GEMM_BLOCKS) {
        int count = cntAB[(size_t)bucket * GEMM_BLOCKS + t];   // coalesced row
        if (count > SEGB) count = SEGB;
        const uint2* cell = seg + ((size_t)t * NBUCK + bucket) * SEGB;
        for (int i = 0; i < count; ++i) {
            uint2 en = cell[i];
            int ln = (int)en.y;
            int pos = atomicAdd(&lcnt[ln], 1);
            if (pos < CAP_A)
                lslot[ln][pos] = en.x;
            else if (pos < CAP)
                slotB[(size_t)(bucket * 256 + ln) * CAP_B + (pos - CAP_A)] = en.x;
        }
    }
    __syncthreads();

    if (t < 256) cnt[bucket * 256 + t] = lcnt[t];
    uint4* ap = (uint4*)(slotA + (size_t)bucket * 256 * CAP_A);
    const uint4* ls = (const uint4*)&lslot[0][0];
#pragma unroll
    for (int i = 0; i < 2; ++i)
        ap[t + 512 * i] = ls[t + 512 * i];
}

// ---------------- gather (verbatim r24/r26; nontemporal out stores) ----------
__device__ __forceinline__ float bf_lo(unsigned u) {
    return __uint_as_float(u << 16);
}
__device__ __forceinline__ float bf_hi(unsigned u) {
    return __uint_as_float(u & 0xFFFF0000u);
}

#define ACC8(A, W, Y4)                                        \
    A[0] += (W) * bf_lo((Y4).x); A[1] += (W) * bf_hi((Y4).x); \
    A[2] += (W) * bf_lo((Y4).y); A[3] += (W) * bf_hi((Y4).y); \
    A[4] += (W) * bf_lo((Y4).z); A[5] += (W) * bf_hi((Y4).z); \
    A[6] += (W) * bf_lo((Y4).w); A[7] += (W) * bf_hi((Y4).w);

__device__ __forceinline__ void chunk16(const uint4* __restrict__ s4, int soff,
                                        int base, int deg,
                                        const ushort* __restrict__ Y, int c,
                                        float* a0, float* a1) {
    int   idx[16];
    float wgt[16];
#pragma unroll
    for (int i = 0; i < 4; ++i) {
        uint4 sv = s4[soff + i];
        int j = base + 4 * i;
        idx[4 * i + 0] = (j + 0 < deg) ? (int)(sv.x & 0xFFFFu) : 0;
        wgt[4 * i + 0] = (j + 0 < deg) ? bf_hi(sv.x) : 0.f;
        idx[4 * i + 1] = (j + 1 < deg) ? (int)(sv.y & 0xFFFFu) : 0;
        wgt[4 * i + 1] = (j + 1 < deg) ? bf_hi(sv.y) : 0.f;
        idx[4 * i + 2] = (j + 2 < deg) ? (int)(sv.z & 0xFFFFu) : 0;
        wgt[4 * i + 2] = (j + 2 < deg) ? bf_hi(sv.z) : 0.f;
        idx[4 * i + 3] = (j + 3 < deg) ? (int)(sv.w & 0xFFFFu) : 0;
        wgt[4 * i + 3] = (j + 3 < deg) ? bf_hi(sv.w) : 0.f;
    }
    uint4 y[16];
#pragma unroll
    for (int i = 0; i < 16; ++i)
        y[i] = *(const uint4*)(Y + (size_t)idx[i] * DIM + c);
#pragma unroll
    for (int i = 0; i < 16; i += 2) {
        ACC8(a0, wgt[i], y[i]);
        ACC8(a1, wgt[i + 1], y[i + 1]);
    }
}

__global__ __launch_bounds__(256) void k_gather_ab(
        const ushort* __restrict__ Y,
        const int* __restrict__ cnt,
        const unsigned* __restrict__ slotA,
        const unsigned* __restrict__ slotB,
        const float* __restrict__ bias,
        float* __restrict__ out) {
    int node = blockIdx.x * 16 + (threadIdx.x >> 4);
    if (node >= N_NODES) return;
    int c = (threadIdx.x & 15) * 8;
    int deg = cnt[node];
    if (deg > CAP) deg = CAP;

    float a0[8], a1[8];
#pragma unroll
    for (int k = 0; k < 8; ++k) { a0[k] = 0.f; a1[k] = 0.f; }

    const uint4* a4 = (const uint4*)(slotA + (size_t)node * CAP_A);
    chunk16(a4, 0, 0, deg, Y, c, a0, a1);

    if (deg > CAP_A) {
        const uint4* b4 = (const uint4*)(slotB + (size_t)node * CAP_B);
        for (int base = CAP_A; base < deg; base += 16)
            chunk16(b4, (base - CAP_A) >> 2, base, deg, Y, c, a0, a1);
    }

    float4 bA = *(const float4*)(bias + c);
    float4 bB = *(const float4*)(bias + c + 4);
    float* op = out + (size_t)node * DIM + c;
    floatx4 o0 = {a0[0] + a1[0] + bA.x, a0[1] + a1[1] + bA.y,
                  a0[2] + a1[2] + bA.z, a0[3] + a1[3] + bA.w};
    floatx4 o1 = {a0[4] + a1[4] + bB.x, a0[5] + a1[5] + bB.y,
                  a0[6] + a1[6] + bB.z, a0[7] + a1[7] + bB.w};
    __builtin_nontemporal_store(o0, (floatx4*)(op + 0));
    __builtin_nontemporal_store(o1, (floatx4*)(op + 4));
}

// ---------------- fallback path kernels (ws too small) ----------------
__global__ void zero_ws(float4* __restrict__ p, int n4) {
    int i = blockIdx.x * blockDim.x + threadIdx.x;
    if (i < n4) p[i] = make_float4(0.f, 0.f, 0.f, 0.f);
}

__global__ __launch_bounds__(256) void scatter_edges(
        const float* __restrict__ x,
        const float* __restrict__ ew,
        const int* __restrict__ esrc,
        const int* __restrict__ edst,
        float* __restrict__ agg) {
    long long t = (long long)blockIdx.x * blockDim.x + threadIdx.x;
    int e = (int)(t >> 5);
    if (e >= N_EDGES) return;
    int d4 = ((int)t & 31) * 4;
    int s = esrc[e];
    int d = edst[e];
    float w = ew[e];
    float4 xv = *(const float4*)(x + (size_t)s * DIM + d4);
    float* ap = agg + (size_t)d * DIM + d4;
    atomicAdd(ap + 0, w * xv.x);
    atomicAdd(ap + 1, w * xv.y);
    atomicAdd(ap + 2, w * xv.z);
    atomicAdd(ap + 3, w * xv.w);
}

__global__ __launch_bounds__(256) void gemm_f32_bias(
        const float* __restrict__ A,
        const float* __restrict__ W,
        const float* __restrict__ bias,
        float* __restrict__ out) {
    __shared__ float Ws[DIM][DIM];
    int tid = threadIdx.x;
    const float4* W4 = (const float4*)W;
    float4* Ws4 = (float4*)&Ws[0][0];
#pragma unroll
    for (int i = 0; i < 16; ++i) Ws4[tid + 256 * i] = W4[tid + 256 * i];
    __syncthreads();

    int row0 = blockIdx.x * 64 + (tid >> 5) * 8;
    int cg = (tid & 31) * 4;
    float4 b = *(const float4*)(bias + cg);
    float acc[8][4];
#pragma unroll
    for (int i = 0; i < 8; ++i) {
        acc[i][0] = b.x; acc[i][1] = b.y; acc[i][2] = b.z; acc[i][3] = b.w;
    }
    int rload[8];
#pragma unroll
    for (int i = 0; i < 8; ++i) {
        int r = row0 + i;
        rload[i] = (r < N_NODES) ? r : (N_NODES - 1);
    }
    for (int kt = 0; kt < 32; ++kt) {
        float4 xr[8];
#pragma unroll
        for (int i = 0; i < 8; ++i)
            xr[i] = *(const float4*)(A + (size_t)rload[i] * DIM + kt * 4);
        float4 wr[4];
#pragma unroll
        for (int j = 0; j < 4; ++j)
            wr[j] = *(const float4*)&Ws[kt * 4 + j][cg];
#pragma unroll
        for (int i = 0; i < 8; ++i) {
            acc[i][0] += xr[i].x * wr[0].x + xr[i].y * wr[1].x + xr[i].z * wr[2].x + xr[i].w * wr[3].x;
            acc[i][1] += xr[i].x * wr[0].y + xr[i].y * wr[1].y + xr[i].z * wr[2].y + xr[i].w * wr[3].y;
            acc[i][2] += xr[i].x * wr[0].z + xr[i].y * wr[1].z + xr[i].z * wr[2].z + xr[i].w * wr[3].z;
            acc[i][3] += xr[i].x * wr[0].w + xr[i].y * wr[1].w + xr[i].z * wr[2].w + xr[i].w * wr[3].w;
        }
    }
#pragma unroll
    for (int i = 0; i < 8; ++i) {
        int row = row0 + i;
        if (row >= N_NODES) break;
        *(float4*)(out + (size_t)row * DIM + cg) =
            make_float4(acc[i][0], acc[i][1], acc[i][2], acc[i][3]);
    }
}

extern "C" void kernel_launch(void* const* d_in, const int* in_sizes, int n_in,
                              void* d_out, int out_size, void* d_ws, size_t ws_size,
                              hipStream_t stream) {
    const float* batch_x     = (const float*)d_in[0];
    const float* edge_weight = (const float*)d_in[1];
    const float* weight      = (const float*)d_in[2];
    const float* bias        = (const float*)d_in[3];
    const int*   edge_src    = (const int*)d_in[4];
    const int*   edge_dst    = (const int*)d_in[5];
    float* out = (float*)d_out;

    auto align256 = [](size_t x) { return (x + 255) & ~(size_t)255; };
    char* ws = (char*)d_ws;

    size_t oY    = 0;                                                            // 12.8 MB
    size_t oCnt  = align256(oY + (size_t)N_NODES * DIM * sizeof(ushort));        // 200 KB
    size_t oA    = align256(oCnt + (size_t)NPAD * sizeof(int));                  // 3.2 MB
    size_t oB    = align256(oA + (size_t)NPAD * CAP_A * sizeof(unsigned));       // 9.6 MB
    size_t oCAB  = align256(oB + (size_t)NPAD * CAP_B * sizeof(unsigned));       // 306 KB
    size_t oSeg  = align256(oCAB + (size_t)GEMM_BLOCKS * NBUCK * sizeof(int));   // 19.6 MB
    size_t needed = oSeg + (size_t)GEMM_BLOCKS * NBUCK * SEGB * sizeof(uint2);

    if (ws_size >= needed) {
        ushort*   Y     = (ushort*)(ws + oY);
        int*      cnt   = (int*)(ws + oCnt);
        unsigned* slotA = (unsigned*)(ws + oA);
        unsigned* slotB = (unsigned*)(ws + oB);
        int*      cntAB = (int*)(ws + oCAB);
        uint2*    seg   = (uint2*)(ws + oSeg);

        // 1) fused gemm (inline W prep) + phase-A bucketing
        k_gemm_fill<<<GEMM_BLOCKS, 512, 0, stream>>>(
            batch_x, weight, Y, edge_src, edge_dst, edge_weight, seg, cntAB);

        // 2) phase B: buckets -> per-node slots
        k_binslot<<<NBUCK, 512, 0, stream>>>(seg, cntAB, cnt, slotA, slotB);

        // 3) gather + bias (nontemporal out stores)
        k_gather_ab<<<(N_NODES + 15) / 16, 256, 0, stream>>>(
            Y, cnt, slotA, slotB, bias, out);
    } else {
        // fallback: atomic path (needs 25.6 MB)
        float* agg = (float*)d_ws;
        int n4 = N_NODES * DIM / 4;
        zero_ws<<<(n4 + 255) / 256, 256, 0, stream>>>((float4*)agg, n4);
        long long threads = (long long)N_EDGES * 32;
        scatter_edges<<<(int)((threads + 255) / 256), 256, 0, stream>>>(
            batch_x, edge_weight, edge_src, edge_dst, agg);
        gemm_f32_bias<<<(N_NODES + 63) / 64, 256, 0, stream>>>(
            agg, weight, bias, out);
    }
}